// Round 5
// baseline (344.882 us; speedup 1.0000x reference)
//
#include <hip/hip_runtime.h>
#include <math.h>

#define MM 512
#define KK 100000
#define NB1 1024               // pass1/corr blocks (4 waves each -> 4096 waves)
#define NW  (NB1 * 4)          // total waves in pass kernels
#define SSTR 32                // per-wave s stride (myN <= 25 < 32), contiguous layout
#define NVU 16                 // k_vu blocks (partial slabs)
#define NCHUNK 16              // corr reduction chunks (64 blocks each)

// ws float layout:
// [1024]       sumU = sum_i x_i . u
// [1025]       Z    (atomic-accumulated, raw)
// [1026..1042) cntc[16] per-chunk arrival counters (int)
// [1042]       cnt2 chunk-finish counter (int)
// [1536..2048) acc (cross-chunk accumulator)
// [2048..3072) pmax (per-block m_blk = max_i s_i; written unconditionally)
// [3072..4096) zpart (per-block Ez_blk; written unconditionally)
// [4096..12288)    vpart[16][512] (k_vu partials, non-atomic)
// [12288..20480)   upart[16][512]
// [32768..163840)  s: per-wave CONTIGUOUS, s[gw*32 + k]  (4096 waves x 32)
// [196608..720896) part: per-block E partials (pass1), rescaled+corrected (corr)
// NO memset: k_vu block 0 zeroes the scalar/counter/acc region.

__device__ inline float waveSum(float v){
  #pragma unroll
  for(int off = 32; off > 0; off >>= 1) v += __shfl_down(v, off, 64);
  return v;   // total in lane 0
}
__device__ inline float waveMax(float v){
  #pragma unroll
  for(int off = 32; off > 0; off >>= 1) v = fmaxf(v, __shfl_down(v, off, 64));
  return v;
}
__device__ inline float dot8(float4 x0, float4 x1, float4 v0, float4 v1){
  return x0.x*v0.x + x0.y*v0.y + x0.z*v0.z + x0.w*v0.w
       + x1.x*v1.x + x1.y*v1.y + x1.z*v1.z + x1.w*v1.w;
}
__device__ inline void fma4(float4& acc, float w, float4 x){
  acc.x += w * x.x; acc.y += w * x.y; acc.z += w * x.z; acc.w += w * x.w;
}
__device__ inline void scale4(float4& v, float s){
  v.x *= s; v.y *= s; v.z *= s; v.w *= s;
}

// Per-slab partials: vpart[b][j] = sum_{k in slab b} W[k,j] a1[k] (no atomics,
// no zero-init needed).  Block 0 additionally zeroes the scalar/counter/acc
// region (nobody reads those until later kernels).
__global__ __launch_bounds__(512) void k_vu(const float* __restrict__ W,
                                            const float* __restrict__ a,
                                            float* __restrict__ vpart,
                                            float* __restrict__ upart,
                                            float* __restrict__ ws){
  int j  = threadIdx.x;
  int b  = blockIdx.x;
  int k0 = b * (MM / NVU);           // 32 rows per slab
  float pv = 0.f, pu = 0.f;
  #pragma unroll 8
  for(int kk = 0; kk < MM / NVU; kk++){
    float w = W[(size_t)(k0 + kk) * MM + j];
    pv += w * a[k0 + kk];
    pu += w * a[MM + k0 + kk];
  }
  vpart[b * MM + j] = pv;
  upart[b * MM + j] = pu;
  if(b == 0){
    if(j < 128) ws[1024 + j] = 0.f;   // sumU, Z, cntc[16], cnt2, padding
    ws[1536 + j] = 0.f;               // acc
  }
}

// Pass 1 (online): prologue reduces vpart/upart into LDS; then per row
// s_i = x_i.v (4-row batched butterfly), sumU += x_i.u, ONLINE accumulate
// E = sum_i exp(s_i - m_w) * x_i with running per-wave max (flash-style).
// Cross-wave combine to part[b][512] at block max; pmax[b], zpart[b].
__global__ __launch_bounds__(256) void k_pass1o(const float* __restrict__ x,
                                                const float* __restrict__ vpart,
                                                const float* __restrict__ upart,
                                                float* __restrict__ s,
                                                float* __restrict__ sumU,
                                                float* __restrict__ pmax,
                                                float* __restrict__ part,
                                                float* __restrict__ zpart){
  __shared__ float lsum[4];
  __shared__ float lmax[4];
  __shared__ float ezs[4];
  __shared__ float lw[2048];   // 4 waves x 64 lanes x 8 cols
  __shared__ float vul[1024];  // reduced v (0..512) and u (512..1024)
  int tid  = threadIdx.x;
  int lane = tid & 63;
  int wid  = tid >> 6;
  int gw   = blockIdx.x * 4 + wid;

  // ---- prologue: reduce the 16 v/u slabs into LDS ----
  #pragma unroll
  for(int jj = 0; jj < 2; jj++){
    int j = tid + jj * 256;
    float sv = 0.f, su = 0.f;
    #pragma unroll
    for(int bb = 0; bb < NVU; bb++){
      sv += vpart[bb * MM + j];
      su += upart[bb * MM + j];
    }
    vul[j]       = sv;
    vul[512 + j] = su;
  }
  __syncthreads();

  const float4* v4 = (const float4*)vul;
  const float4* u4 = (const float4*)(vul + 512);
  float4 v0 = v4[lane],      v1 = v4[64 + lane];
  float4 u0 = u4[lane],      u1 = u4[64 + lane];
  float accU = 0.f;
  float m_w  = -3.4e38f;
  float Ez   = 0.f;
  float4 E0 = make_float4(0,0,0,0), E1 = make_float4(0,0,0,0);

  int myN = (KK - 1 - gw) / NW + 1;   // rows this wave owns (24 or 25)
  int k = 0;
  for(; k + 4 <= myN; k += 4){
    size_t r0 = (size_t)gw + (size_t)(k + 0) * NW;
    size_t r1 = (size_t)gw + (size_t)(k + 1) * NW;
    size_t r2 = (size_t)gw + (size_t)(k + 2) * NW;
    size_t r3 = (size_t)gw + (size_t)(k + 3) * NW;
    const float4* pa = (const float4*)(x + r0 * MM);
    const float4* pb = (const float4*)(x + r1 * MM);
    const float4* pc = (const float4*)(x + r2 * MM);
    const float4* pd = (const float4*)(x + r3 * MM);
    float4 xa0 = pa[lane], xa1 = pa[64 + lane];
    float4 xb0 = pb[lane], xb1 = pb[64 + lane];
    float4 xc0 = pc[lane], xc1 = pc[64 + lane];
    float4 xd0 = pd[lane], xd1 = pd[64 + lane];
    float d0 = dot8(xa0, xa1, v0, v1);  accU += dot8(xa0, xa1, u0, u1);
    float d1 = dot8(xb0, xb1, v0, v1);  accU += dot8(xb0, xb1, u0, u1);
    float d2 = dot8(xc0, xc1, v0, v1);  accU += dot8(xc0, xc1, u0, u1);
    float d3 = dot8(xd0, xd1, v0, v1);  accU += dot8(xd0, xd1, u0, u1);
    #pragma unroll
    for(int off = 1; off < 64; off <<= 1){
      d0 += __shfl_xor(d0, off, 64);
      d1 += __shfl_xor(d1, off, 64);
      d2 += __shfl_xor(d2, off, 64);
      d3 += __shfl_xor(d3, off, 64);
    }
    // online max update (wave-uniform: d* identical in all lanes)
    float g = fmaxf(fmaxf(d0, d1), fmaxf(d2, d3));
    if(g > m_w){
      float sc = __expf(m_w - g);     // exp(-inf)=0 on first group: E stays 0
      scale4(E0, sc); scale4(E1, sc); Ez *= sc;
      m_w = g;
    }
    float w0 = __expf(d0 - m_w);
    float w1 = __expf(d1 - m_w);
    float w2 = __expf(d2 - m_w);
    float w3 = __expf(d3 - m_w);
    Ez += w0 + w1 + w2 + w3;
    fma4(E0, w0, xa0); fma4(E1, w0, xa1);
    fma4(E0, w1, xb0); fma4(E1, w1, xb1);
    fma4(E0, w2, xc0); fma4(E1, w2, xc1);
    fma4(E0, w3, xd0); fma4(E1, w3, xd1);
    // store s (lanes 0..3, contiguous 16B)
    float s0 = (lane & 1) ? d1 : d0;
    float s1 = (lane & 1) ? d3 : d2;
    float rr = (lane & 2) ? s1 : s0;
    if(lane < 4) s[gw * SSTR + k + lane] = rr;
  }
  for(; k < myN; k++){
    size_t row = (size_t)gw + (size_t)k * NW;
    const float4* xr = (const float4*)(x + row * MM);
    float4 x0 = xr[lane];
    float4 x1 = xr[64 + lane];
    float d = dot8(x0, x1, v0, v1);
    accU += dot8(x0, x1, u0, u1);
    #pragma unroll
    for(int off = 1; off < 64; off <<= 1) d += __shfl_xor(d, off, 64);
    if(d > m_w){
      float sc = __expf(m_w - d);
      scale4(E0, sc); scale4(E1, sc); Ez *= sc;
      m_w = d;
    }
    float w = __expf(d - m_w);
    Ez += w;
    fma4(E0, w, x0); fma4(E1, w, x1);
    if(lane == 0) s[gw * SSTR + k] = d;
  }

  // ---- tail: rescale to block max, cross-wave combine, write partials ----
  float us = waveSum(accU);
  if(lane == 0){ lsum[wid] = us; lmax[wid] = m_w; }
  __syncthreads();
  float m_blk = fmaxf(fmaxf(lmax[0], lmax[1]), fmaxf(lmax[2], lmax[3]));
  float sc2 = __expf(m_w - m_blk);    // wave-uniform
  scale4(E0, sc2); scale4(E1, sc2);
  if(lane == 0) ezs[wid] = Ez * sc2;
  float4* lw4 = (float4*)lw;
  lw4[wid * 128 + lane * 2]     = E0;   // lane l holds cols 4l+q
  lw4[wid * 128 + lane * 2 + 1] = E1;   // and cols 256+4l+q
  __syncthreads();
  int l = tid >> 2, q = tid & 3;
  float o0 = lw[0*512 + l*8 + q] + lw[1*512 + l*8 + q]
           + lw[2*512 + l*8 + q] + lw[3*512 + l*8 + q];
  float o1 = lw[0*512 + l*8 + 4 + q] + lw[1*512 + l*8 + 4 + q]
           + lw[2*512 + l*8 + 4 + q] + lw[3*512 + l*8 + 4 + q];
  part[(size_t)blockIdx.x * 512 + tid]       = o0;
  part[(size_t)blockIdx.x * 512 + 256 + tid] = o1;
  if(tid == 0){
    atomicAdd(sumU, lsum[0] + lsum[1] + lsum[2] + lsum[3]);
    pmax[blockIdx.x]  = m_blk;
    zpart[blockIdx.x] = ezs[0] + ezs[1] + ezs[2] + ezs[3];
  }
}

// Correction pass + folded final reduction.
// Main: compute c, M; re-read ONLY clipped rows (s_i + c < 0), accumulate
// C = sum_clip (e^-M - e^(t-M)) x_i; rescale block's E partial in place; Z.
// Tail: per-chunk done-counter -> 64th arriver ACQUIRE-fences (invalidate
// stale XCD-L2 lines of part) then reduces its chunk into acc; 16th
// chunk-finisher divides by Z and writes out.
__global__ __launch_bounds__(256) void k_corr(const float* __restrict__ x,
                                              const float* __restrict__ s,
                                              const float* __restrict__ b,
                                              const float* __restrict__ a,
                                              const float* __restrict__ sumU,
                                              const float* __restrict__ pmax,
                                              float* __restrict__ part,
                                              const float* __restrict__ zpart,
                                              float* __restrict__ Z,
                                              float* __restrict__ acc,
                                              int* __restrict__ cntc,
                                              int* __restrict__ cnt2,
                                              float* __restrict__ out){
  __shared__ float red[8];
  __shared__ float czs[4];
  __shared__ float lw[2048];
  __shared__ int sArr;
  __shared__ int sFin;
  int tid  = threadIdx.x;
  int lane = tid & 63;
  int wid  = tid >> 6;
  int gw   = blockIdx.x * 4 + wid;

  // ---- prologue: c = b.(a1+a2) + sumU/K ; M = max(0, max_i s_i + c) ----
  float tp = b[tid]       * (a[tid]       + a[MM + tid])
           + b[tid + 256] * (a[tid + 256] + a[MM + tid + 256]);
  float mx = fmaxf(fmaxf(pmax[tid], pmax[tid + 256]),
                   fmaxf(pmax[tid + 512], pmax[tid + 768]));
  float wsum = waveSum(tp);
  mx = waveMax(mx);
  if(lane == 0){ red[wid] = wsum; red[4 + wid] = mx; }
  __syncthreads();
  float c  = sumU[0] * (1.0f / (float)KK) + red[0] + red[1] + red[2] + red[3];
  float mg = fmaxf(fmaxf(red[4], red[5]), fmaxf(red[6], red[7]));
  float M  = fmaxf(0.f, mg + c);
  float eM = __expf(-M);

  // ---- clipped-row loop (wave-uniform branch; ~50% of rows) ----
  float4 C0 = make_float4(0,0,0,0), C1 = make_float4(0,0,0,0);
  float Cz = 0.f;
  int myN = (KK - 1 - gw) / NW + 1;
  const float4* s4 = (const float4*)(s + gw * SSTR);
  #pragma unroll
  for(int g2 = 0; g2 < 7; g2++){
    int kb = g2 * 4;
    if(kb >= myN) break;
    float4 sv = s4[g2];
    {
      int k = kb + 0;
      float t = sv.x + c;
      if(k < myN && t < 0.f){
        float kap = eM - __expf(t - M);
        size_t row = (size_t)gw + (size_t)k * NW;
        const float4* xr = (const float4*)(x + row * MM);
        float4 x0 = xr[lane], x1 = xr[64 + lane];
        fma4(C0, kap, x0); fma4(C1, kap, x1); Cz += kap;
      }
    }
    {
      int k = kb + 1;
      float t = sv.y + c;
      if(k < myN && t < 0.f){
        float kap = eM - __expf(t - M);
        size_t row = (size_t)gw + (size_t)k * NW;
        const float4* xr = (const float4*)(x + row * MM);
        float4 x0 = xr[lane], x1 = xr[64 + lane];
        fma4(C0, kap, x0); fma4(C1, kap, x1); Cz += kap;
      }
    }
    {
      int k = kb + 2;
      float t = sv.z + c;
      if(k < myN && t < 0.f){
        float kap = eM - __expf(t - M);
        size_t row = (size_t)gw + (size_t)k * NW;
        const float4* xr = (const float4*)(x + row * MM);
        float4 x0 = xr[lane], x1 = xr[64 + lane];
        fma4(C0, kap, x0); fma4(C1, kap, x1); Cz += kap;
      }
    }
    {
      int k = kb + 3;
      float t = sv.w + c;
      if(k < myN && t < 0.f){
        float kap = eM - __expf(t - M);
        size_t row = (size_t)gw + (size_t)k * NW;
        const float4* xr = (const float4*)(x + row * MM);
        float4 x0 = xr[lane], x1 = xr[64 + lane];
        fma4(C0, kap, x0); fma4(C1, kap, x1); Cz += kap;
      }
    }
  }

  // ---- combine C across waves; rescale+correct part in place; Z ----
  __syncthreads();                 // red fully consumed above
  float4* lw4 = (float4*)lw;
  lw4[wid * 128 + lane * 2]     = C0;
  lw4[wid * 128 + lane * 2 + 1] = C1;
  if(lane == 0) czs[wid] = Cz;     // Cz identical across lanes (uniform kap)
  __syncthreads();
  int l = tid >> 2, q = tid & 3;
  float o0 = lw[0*512 + l*8 + q] + lw[1*512 + l*8 + q]
           + lw[2*512 + l*8 + q] + lw[3*512 + l*8 + q];
  float o1 = lw[0*512 + l*8 + 4 + q] + lw[1*512 + l*8 + 4 + q]
           + lw[2*512 + l*8 + 4 + q] + lw[3*512 + l*8 + 4 + q];
  float scB = __expf(c - M + pmax[blockIdx.x]);   // <= 1 by construction
  size_t base = (size_t)blockIdx.x * 512;
  part[base + tid]       = part[base + tid]       * scB + o0;
  part[base + 256 + tid] = part[base + 256 + tid] * scB + o1;
  if(tid == 0)
    atomicAdd(Z, czs[0] + czs[1] + czs[2] + czs[3] + scB * zpart[blockIdx.x]);

  // ---- folded reduction: 64th arriver of each 64-block chunk reduces it ----
  // Protocol (validated by round-1 fused kernel, absmax 0.0):
  //   writer: stores drained by barrier -> RELEASE threadfence -> counter inc
  //   reader: counter inc observed      -> ACQUIRE threadfence -> plain loads
  // The acquire fence invalidates stale-but-valid part lines in this block's
  // XCD L2 (per-XCD L2s are not cross-coherent). Conditional on being the
  // last arriver so the other 1008 blocks don't evict live x lines.
  __syncthreads();                 // drain part stores to L2
  if(tid == 0){
    __threadfence();               // release: write back this XCD's dirty lines
    sArr = atomicAdd(&cntc[blockIdx.x >> 6], 1);
    if(sArr == 63) __threadfence();  // acquire: invalidate stale L2 lines
  }
  __syncthreads();
  if(sArr == 63){                  // all 64 blocks of this chunk have published
    int g = blockIdx.x >> 6;
    const float* p = part + (size_t)g * 64 * 512;
    float r0 = 0.f, r1 = 0.f;
    #pragma unroll 8
    for(int bb = 0; bb < 64; bb++){
      r0 += p[bb * 512 + tid];
      r1 += p[bb * 512 + 256 + tid];
    }
    atomicAdd(&acc[tid],       r0);
    atomicAdd(&acc[tid + 256], r1);
    __threadfence();
    if(tid == 0) sFin = atomicAdd(cnt2, 1);
    __syncthreads();
    if(sFin == NCHUNK - 1){        // all chunks accumulated; Z complete too
      float z   = atomicAdd(Z, 0.0f);                // coherent read
      float v0r = atomicAdd(&acc[tid],       0.0f);  // coherent read of atomics
      float v1r = atomicAdd(&acc[tid + 256], 0.0f);
      out[tid]       = v0r / z;
      out[tid + 256] = v1r / z;
    }
  }
}

extern "C" void kernel_launch(void* const* d_in, const int* in_sizes, int n_in,
                              void* d_out, int out_size, void* d_ws, size_t ws_size,
                              hipStream_t stream) {
  const float* x = (const float*)d_in[0];
  const float* W = (const float*)d_in[1];
  const float* b = (const float*)d_in[2];
  const float* a = (const float*)d_in[3];
  float* ws  = (float*)d_ws;
  float* out = (float*)d_out;

  float* sumU  = ws + 1024;
  float* Z     = ws + 1025;
  int*   cntc  = (int*)(ws + 1026);
  int*   cnt2  = (int*)(ws + 1042);
  float* acc   = ws + 1536;
  float* pmax  = ws + 2048;
  float* zpart = ws + 3072;
  float* vpart = ws + 4096;
  float* upart = ws + 12288;
  float* s     = ws + 32768;
  float* part  = ws + 196608;

  k_vu    <<<NVU,  512, 0, stream>>>(W, a, vpart, upart, ws);
  k_pass1o<<<NB1,  256, 0, stream>>>(x, vpart, upart, s, sumU, pmax, part, zpart);
  k_corr  <<<NB1,  256, 0, stream>>>(x, s, b, a, sumU, pmax, part, zpart, Z,
                                     acc, cntc, cnt2, out);
}

// Round 6
// 322.455 us; speedup vs baseline: 1.0696x; 1.0696x over previous
//
#include <hip/hip_runtime.h>
#include <math.h>

#define MM 512
#define KK 100000
#define NB1 1024               // pass1/corr blocks (4 waves each -> 4096 waves)
#define NW  (NB1 * 4)          // total waves in pass kernels
#define SSTR 32                // per-wave s stride (myN <= 25 < 32), contiguous layout
#define NVU 16                 // k_vu blocks (partial slabs)
#define NOUT 16                // k_out blocks
#define THR 0.2f               // pass1 bucket threshold: s < -THR -> plain-sum bucket

// ws float layout:
// [1024]       sumU = sum_i x_i . u
// [1025]       Z    (atomic-accumulated, raw)
// [1026]       done-counter for k_out (int)
// [1536..2048) acc (k_out cross-block accumulator)
// [2048..3072) pmax (per-block m_blk = max over E-rows of s; unconditional)
// [3072..4096) zpart (per-block Ez_blk)
// [4096..12288)    vpart[16][512] (k_vu partials, non-atomic)
// [12288..20480)   upart[16][512]
// [20480..21504)   nclipa (per-block count of P-rows, float)
// [32768..163840)  s: per-wave CONTIGUOUS, s[gw*32 + k]  (4096 waves x 32)
// [196608..720896)  Epart[b][512]: online-E partials; corr overwrites with final
// [720896..1245184) Ppart[b][512]: plain colsum of P-rows (s < -THR)
// NO memset: k_vu block 0 zeroes the scalar/counter/acc region.

__device__ inline float waveSum(float v){
  #pragma unroll
  for(int off = 32; off > 0; off >>= 1) v += __shfl_down(v, off, 64);
  return v;   // total in lane 0
}
__device__ inline float waveMax(float v){
  #pragma unroll
  for(int off = 32; off > 0; off >>= 1) v = fmaxf(v, __shfl_down(v, off, 64));
  return v;
}
__device__ inline float dot8(float4 x0, float4 x1, float4 v0, float4 v1){
  return x0.x*v0.x + x0.y*v0.y + x0.z*v0.z + x0.w*v0.w
       + x1.x*v1.x + x1.y*v1.y + x1.z*v1.z + x1.w*v1.w;
}
__device__ inline void fma4(float4& acc, float w, float4 x){
  acc.x += w * x.x; acc.y += w * x.y; acc.z += w * x.z; acc.w += w * x.w;
}
__device__ inline void add4(float4& acc, float4 x){
  acc.x += x.x; acc.y += x.y; acc.z += x.z; acc.w += x.w;
}
__device__ inline void scale4(float4& v, float s){
  v.x *= s; v.y *= s; v.z *= s; v.w *= s;
}

// Per-slab partials: vpart[b][j] = sum_{k in slab b} W[k,j] a1[k] (no atomics,
// no zero-init).  Block 0 zeroes the scalar/counter/acc region.
__global__ __launch_bounds__(512) void k_vu(const float* __restrict__ W,
                                            const float* __restrict__ a,
                                            float* __restrict__ vpart,
                                            float* __restrict__ upart,
                                            float* __restrict__ ws){
  int j  = threadIdx.x;
  int b  = blockIdx.x;
  int k0 = b * (MM / NVU);           // 32 rows per slab
  float pv = 0.f, pu = 0.f;
  #pragma unroll 8
  for(int kk = 0; kk < MM / NVU; kk++){
    float w = W[(size_t)(k0 + kk) * MM + j];
    pv += w * a[k0 + kk];
    pu += w * a[MM + k0 + kk];
  }
  vpart[b * MM + j] = pv;
  upart[b * MM + j] = pu;
  if(b == 0){
    if(j < 128) ws[1024 + j] = 0.f;   // sumU, Z, cnt, padding
    ws[1536 + j] = 0.f;               // acc
  }
}

// Pass 1 (online + bucketed): prologue reduces vpart/upart into LDS; per row
// s_i = x_i.v (4-row batched butterfly), sumU += x_i.u, then BUCKET:
//   s_i <  -THR : P += x_i (plain colsum), nclip++   (weight e^-M if t<0)
//   s_i >= -THR : online E += exp(s_i - m_w) x_i (flash-style running max)
// Tail: combine E at block max -> Epart[b], combine P -> Ppart[b];
// pmax[b]=m_blk, zpart[b]=Ez_blk, nclipa[b]=count.
__global__ __launch_bounds__(256) void k_pass1o(const float* __restrict__ x,
                                                const float* __restrict__ vpart,
                                                const float* __restrict__ upart,
                                                float* __restrict__ s,
                                                float* __restrict__ sumU,
                                                float* __restrict__ pmax,
                                                float* __restrict__ Epart,
                                                float* __restrict__ Ppart,
                                                float* __restrict__ zpart,
                                                float* __restrict__ nclipa){
  __shared__ float lsum[4];
  __shared__ float lmax[4];
  __shared__ float ezs[4];
  __shared__ float ncs[4];
  __shared__ float lw[2048];   // 4 waves x 64 lanes x 8 cols
  __shared__ float vul[1024];  // reduced v (0..512) and u (512..1024)
  int tid  = threadIdx.x;
  int lane = tid & 63;
  int wid  = tid >> 6;
  int gw   = blockIdx.x * 4 + wid;

  // ---- prologue: reduce the 16 v/u slabs into LDS ----
  #pragma unroll
  for(int jj = 0; jj < 2; jj++){
    int j = tid + jj * 256;
    float sv = 0.f, su = 0.f;
    #pragma unroll
    for(int bb = 0; bb < NVU; bb++){
      sv += vpart[bb * MM + j];
      su += upart[bb * MM + j];
    }
    vul[j]       = sv;
    vul[512 + j] = su;
  }
  __syncthreads();

  const float4* v4 = (const float4*)vul;
  const float4* u4 = (const float4*)(vul + 512);
  float4 v0 = v4[lane],      v1 = v4[64 + lane];
  float4 u0 = u4[lane],      u1 = u4[64 + lane];
  float accU = 0.f;
  float m_w  = -3.4e38f;
  float Ez   = 0.f;
  float ncl  = 0.f;
  float4 E0 = make_float4(0,0,0,0), E1 = make_float4(0,0,0,0);
  float4 P0 = make_float4(0,0,0,0), P1 = make_float4(0,0,0,0);

  int myN = (KK - 1 - gw) / NW + 1;   // rows this wave owns (24 or 25)
  int k = 0;
  for(; k + 4 <= myN; k += 4){
    size_t r0 = (size_t)gw + (size_t)(k + 0) * NW;
    size_t r1 = (size_t)gw + (size_t)(k + 1) * NW;
    size_t r2 = (size_t)gw + (size_t)(k + 2) * NW;
    size_t r3 = (size_t)gw + (size_t)(k + 3) * NW;
    const float4* pa = (const float4*)(x + r0 * MM);
    const float4* pb = (const float4*)(x + r1 * MM);
    const float4* pc = (const float4*)(x + r2 * MM);
    const float4* pd = (const float4*)(x + r3 * MM);
    float4 xa0 = pa[lane], xa1 = pa[64 + lane];
    float4 xb0 = pb[lane], xb1 = pb[64 + lane];
    float4 xc0 = pc[lane], xc1 = pc[64 + lane];
    float4 xd0 = pd[lane], xd1 = pd[64 + lane];
    float d0 = dot8(xa0, xa1, v0, v1);  accU += dot8(xa0, xa1, u0, u1);
    float d1 = dot8(xb0, xb1, v0, v1);  accU += dot8(xb0, xb1, u0, u1);
    float d2 = dot8(xc0, xc1, v0, v1);  accU += dot8(xc0, xc1, u0, u1);
    float d3 = dot8(xd0, xd1, v0, v1);  accU += dot8(xd0, xd1, u0, u1);
    #pragma unroll
    for(int off = 1; off < 64; off <<= 1){
      d0 += __shfl_xor(d0, off, 64);
      d1 += __shfl_xor(d1, off, 64);
      d2 += __shfl_xor(d2, off, 64);
      d3 += __shfl_xor(d3, off, 64);
    }
    // bucket flags (wave-uniform: d* identical in all lanes)
    bool p0b = d0 < -THR, p1b = d1 < -THR, p2b = d2 < -THR, p3b = d3 < -THR;
    // online max over E-rows of this group only
    float e0 = p0b ? -3.4e38f : d0;
    float e1 = p1b ? -3.4e38f : d1;
    float e2 = p2b ? -3.4e38f : d2;
    float e3 = p3b ? -3.4e38f : d3;
    float g = fmaxf(fmaxf(e0, e1), fmaxf(e2, e3));
    if(g > m_w){
      float sc = __expf(m_w - g);     // exp(-inf)=0 on first E-group: E stays 0
      scale4(E0, sc); scale4(E1, sc); Ez *= sc;
      m_w = g;
    }
    if(p0b){ add4(P0, xa0); add4(P1, xa1); ncl += 1.f; }
    else   { float w = __expf(d0 - m_w); Ez += w; fma4(E0, w, xa0); fma4(E1, w, xa1); }
    if(p1b){ add4(P0, xb0); add4(P1, xb1); ncl += 1.f; }
    else   { float w = __expf(d1 - m_w); Ez += w; fma4(E0, w, xb0); fma4(E1, w, xb1); }
    if(p2b){ add4(P0, xc0); add4(P1, xc1); ncl += 1.f; }
    else   { float w = __expf(d2 - m_w); Ez += w; fma4(E0, w, xc0); fma4(E1, w, xc1); }
    if(p3b){ add4(P0, xd0); add4(P1, xd1); ncl += 1.f; }
    else   { float w = __expf(d3 - m_w); Ez += w; fma4(E0, w, xd0); fma4(E1, w, xd1); }
    // store s (lanes 0..3, contiguous 16B)
    float s0 = (lane & 1) ? d1 : d0;
    float s1 = (lane & 1) ? d3 : d2;
    float rr = (lane & 2) ? s1 : s0;
    if(lane < 4) s[gw * SSTR + k + lane] = rr;
  }
  for(; k < myN; k++){
    size_t row = (size_t)gw + (size_t)k * NW;
    const float4* xr = (const float4*)(x + row * MM);
    float4 x0 = xr[lane];
    float4 x1 = xr[64 + lane];
    float d = dot8(x0, x1, v0, v1);
    accU += dot8(x0, x1, u0, u1);
    #pragma unroll
    for(int off = 1; off < 64; off <<= 1) d += __shfl_xor(d, off, 64);
    if(d < -THR){
      add4(P0, x0); add4(P1, x1); ncl += 1.f;
    } else {
      if(d > m_w){
        float sc = __expf(m_w - d);
        scale4(E0, sc); scale4(E1, sc); Ez *= sc;
        m_w = d;
      }
      float w = __expf(d - m_w);
      Ez += w;
      fma4(E0, w, x0); fma4(E1, w, x1);
    }
    if(lane == 0) s[gw * SSTR + k] = d;
  }

  // ---- tail: rescale E to block max, combine E then P, write partials ----
  float us = waveSum(accU);
  if(lane == 0){ lsum[wid] = us; lmax[wid] = m_w; ncs[wid] = ncl; }
  __syncthreads();
  float m_blk = fmaxf(fmaxf(lmax[0], lmax[1]), fmaxf(lmax[2], lmax[3]));
  float sc2 = __expf(m_w - m_blk);    // wave-uniform; 0 if wave had no E-rows
  scale4(E0, sc2); scale4(E1, sc2);
  if(lane == 0) ezs[wid] = Ez * sc2;
  float4* lw4 = (float4*)lw;
  lw4[wid * 128 + lane * 2]     = E0;   // lane l holds cols 4l+q
  lw4[wid * 128 + lane * 2 + 1] = E1;   // and cols 256+4l+q
  __syncthreads();
  int l = tid >> 2, q = tid & 3;
  float o0 = lw[0*512 + l*8 + q] + lw[1*512 + l*8 + q]
           + lw[2*512 + l*8 + q] + lw[3*512 + l*8 + q];
  float o1 = lw[0*512 + l*8 + 4 + q] + lw[1*512 + l*8 + 4 + q]
           + lw[2*512 + l*8 + 4 + q] + lw[3*512 + l*8 + 4 + q];
  Epart[(size_t)blockIdx.x * 512 + tid]       = o0;
  Epart[(size_t)blockIdx.x * 512 + 256 + tid] = o1;
  __syncthreads();                    // lw fully read; safe to reuse
  lw4[wid * 128 + lane * 2]     = P0;
  lw4[wid * 128 + lane * 2 + 1] = P1;
  __syncthreads();
  float q0 = lw[0*512 + l*8 + q] + lw[1*512 + l*8 + q]
           + lw[2*512 + l*8 + q] + lw[3*512 + l*8 + q];
  float q1 = lw[0*512 + l*8 + 4 + q] + lw[1*512 + l*8 + 4 + q]
           + lw[2*512 + l*8 + 4 + q] + lw[3*512 + l*8 + 4 + q];
  Ppart[(size_t)blockIdx.x * 512 + tid]       = q0;
  Ppart[(size_t)blockIdx.x * 512 + 256 + tid] = q1;
  if(tid == 0){
    atomicAdd(sumU, lsum[0] + lsum[1] + lsum[2] + lsum[3]);
    pmax[blockIdx.x]   = m_blk;
    zpart[blockIdx.x]  = ezs[0] + ezs[1] + ezs[2] + ezs[3];
    nclipa[blockIdx.x] = ncs[0] + ncs[1] + ncs[2] + ncs[3];
  }
}

// Correction pass: compute c, M; re-read ONLY band rows where the pass1
// bucket disagrees with the true clip test: (s < -THR) XOR (s + c < 0).
// delta weight = +-(e^-M - e^(t-M)).  Fold final combine in place:
// part = Epart*scB + Ppart*e^-M + band;  Z += scB*Ez + e^-M*nclip + bandZ.
__global__ __launch_bounds__(256) void k_corr(const float* __restrict__ x,
                                              const float* __restrict__ s,
                                              const float* __restrict__ b,
                                              const float* __restrict__ a,
                                              const float* __restrict__ sumU,
                                              const float* __restrict__ pmax,
                                              float* __restrict__ Epart,
                                              const float* __restrict__ Ppart,
                                              const float* __restrict__ zpart,
                                              const float* __restrict__ nclipa,
                                              float* __restrict__ Z){
  __shared__ float red[8];
  __shared__ float czs[4];
  __shared__ float lw[2048];
  int tid  = threadIdx.x;
  int lane = tid & 63;
  int wid  = tid >> 6;
  int gw   = blockIdx.x * 4 + wid;

  // ---- prologue: c = b.(a1+a2) + sumU/K ; M = max(0, max_i s_i + c) ----
  float tp = b[tid]       * (a[tid]       + a[MM + tid])
           + b[tid + 256] * (a[tid + 256] + a[MM + tid + 256]);
  float mx = fmaxf(fmaxf(pmax[tid], pmax[tid + 256]),
                   fmaxf(pmax[tid + 512], pmax[tid + 768]));
  float wsum = waveSum(tp);
  mx = waveMax(mx);
  if(lane == 0){ red[wid] = wsum; red[4 + wid] = mx; }
  __syncthreads();
  float c  = sumU[0] * (1.0f / (float)KK) + red[0] + red[1] + red[2] + red[3];
  float mg = fmaxf(fmaxf(red[4], red[5]), fmaxf(red[6], red[7]));
  // mg is max over E-rows only; P-rows have s < -THR < mg in practice, and
  // even degenerate cases keep M >= 0 >= t for clipped rows (relu floor).
  float M  = fmaxf(0.f, mg + c);
  float eM = __expf(-M);

  // ---- band loop: rows where (s < -THR) XOR (t < 0); typically ~6-10% ----
  float4 C0 = make_float4(0,0,0,0), C1 = make_float4(0,0,0,0);
  float Cz = 0.f;
  int myN = (KK - 1 - gw) / NW + 1;
  const float4* s4 = (const float4*)(s + gw * SSTR);
  #pragma unroll
  for(int g2 = 0; g2 < 7; g2++){
    int kb = g2 * 4;
    if(kb >= myN) break;
    float4 sv = s4[g2];
    float svv[4] = {sv.x, sv.y, sv.z, sv.w};
    #pragma unroll
    for(int r = 0; r < 4; r++){
      int k = kb + r;
      float si = svv[r];
      float t  = si + c;
      bool pb  = si < -THR;     // pass1 bucket: plain-sum
      bool cl  = t  < 0.f;      // true clip
      if(k < myN && (pb != cl)){
        // pass1-assigned weight: pb ? e^-M : e^(t-M); true: cl ? e^-M : e^(t-M)
        float d  = eM - __expf(t - M);
        float kap = cl ? d : -d;
        size_t row = (size_t)gw + (size_t)k * NW;
        const float4* xr = (const float4*)(x + row * MM);
        float4 x0 = xr[lane], x1 = xr[64 + lane];
        fma4(C0, kap, x0); fma4(C1, kap, x1); Cz += kap;
      }
    }
  }

  // ---- combine band C across waves; fold final partial in place; Z ----
  __syncthreads();                 // red fully consumed above
  float4* lw4 = (float4*)lw;
  lw4[wid * 128 + lane * 2]     = C0;
  lw4[wid * 128 + lane * 2 + 1] = C1;
  if(lane == 0) czs[wid] = Cz;     // Cz identical across lanes (uniform kap)
  __syncthreads();
  int l = tid >> 2, q = tid & 3;
  float o0 = lw[0*512 + l*8 + q] + lw[1*512 + l*8 + q]
           + lw[2*512 + l*8 + q] + lw[3*512 + l*8 + q];
  float o1 = lw[0*512 + l*8 + 4 + q] + lw[1*512 + l*8 + 4 + q]
           + lw[2*512 + l*8 + 4 + q] + lw[3*512 + l*8 + 4 + q];
  float scB = __expf(c - M + pmax[blockIdx.x]);   // <= 1 by construction
  size_t base = (size_t)blockIdx.x * 512;
  Epart[base + tid]       = Epart[base + tid]       * scB
                          + Ppart[base + tid]       * eM + o0;
  Epart[base + 256 + tid] = Epart[base + 256 + tid] * scB
                          + Ppart[base + 256 + tid] * eM + o1;
  if(tid == 0)
    atomicAdd(Z, czs[0] + czs[1] + czs[2] + czs[3]
                 + scB * zpart[blockIdx.x] + eM * nclipa[blockIdx.x]);
}

// Reduce part[1024][512] -> acc, last block divides by Z and writes out.
__global__ __launch_bounds__(256) void k_out(const float* __restrict__ part,
                                             float* __restrict__ acc,
                                             const float* __restrict__ Z,
                                             int* __restrict__ cnt,
                                             float* __restrict__ out){
  __shared__ int lastf;
  int tid = threadIdx.x;
  const float* p = part + (size_t)blockIdx.x * (NB1 / NOUT) * 512;
  float s0 = 0.f, s1 = 0.f;
  #pragma unroll 8
  for(int bb = 0; bb < NB1 / NOUT; bb++){
    s0 += p[bb * 512 + tid];
    s1 += p[bb * 512 + 256 + tid];
  }
  atomicAdd(&acc[tid],       s0);
  atomicAdd(&acc[tid + 256], s1);
  __threadfence();
  if(tid == 0) lastf = (atomicAdd(cnt, 1) == NOUT - 1) ? 1 : 0;
  __syncthreads();
  if(lastf){
    float z = Z[0];   // written by previous dispatch — safe plain read
    float v0 = atomicAdd(&acc[tid],       0.0f);  // coherent read of atomics
    float v1 = atomicAdd(&acc[tid + 256], 0.0f);
    out[tid]       = v0 / z;
    out[tid + 256] = v1 / z;
  }
}

extern "C" void kernel_launch(void* const* d_in, const int* in_sizes, int n_in,
                              void* d_out, int out_size, void* d_ws, size_t ws_size,
                              hipStream_t stream) {
  const float* x = (const float*)d_in[0];
  const float* W = (const float*)d_in[1];
  const float* b = (const float*)d_in[2];
  const float* a = (const float*)d_in[3];
  float* ws  = (float*)d_ws;
  float* out = (float*)d_out;

  float* sumU   = ws + 1024;
  float* Z      = ws + 1025;
  int*   cnt    = (int*)(ws + 1026);
  float* acc    = ws + 1536;
  float* pmax   = ws + 2048;
  float* zpart  = ws + 3072;
  float* vpart  = ws + 4096;
  float* upart  = ws + 12288;
  float* nclipa = ws + 20480;
  float* s      = ws + 32768;
  float* Epart  = ws + 196608;
  float* Ppart  = ws + 720896;

  k_vu    <<<NVU,  512, 0, stream>>>(W, a, vpart, upart, ws);
  k_pass1o<<<NB1,  256, 0, stream>>>(x, vpart, upart, s, sumU, pmax,
                                     Epart, Ppart, zpart, nclipa);
  k_corr  <<<NB1,  256, 0, stream>>>(x, s, b, a, sumU, pmax,
                                     Epart, Ppart, zpart, nclipa, Z);
  k_out   <<<NOUT, 256, 0, stream>>>(Epart, acc, Z, cnt, out);
}

// Round 7
// 316.976 us; speedup vs baseline: 1.0880x; 1.0173x over previous
//
#include <hip/hip_runtime.h>
#include <math.h>

#define MM 512
#define KK 100000
#define NB1 1024               // pass1/corr blocks (4 waves each -> 4096 waves)
#define NW  (NB1 * 4)          // total waves in pass kernels
#define SSTR 32                // per-wave s stride (myN <= 25 < 32), contiguous layout
#define NVU 16                 // k_vu blocks (partial slabs)
#define NOUT 16                // k_out blocks
#define THR 0.2f               // pass1 bucket threshold: s < -THR -> plain-sum bucket

// ws float layout:
// [1024]       sumU = sum_i x_i . u
// [1025]       Z    (atomic-accumulated, raw)
// [1026]       done-counter for k_out (int)
// [1536..2048) acc (k_out cross-block accumulator)
// [2048..3072) pmax (per-block m_blk = max over E-rows of s; unconditional)
// [3072..4096) zpart (per-block Ez_blk)
// [4096..12288)    vpart[16][512] (k_vu partials, non-atomic)
// [12288..20480)   upart[16][512]
// [20480..21504)   nclipa (per-block count of P-rows, float)
// [32768..163840)  s: per-wave CONTIGUOUS, s[gw*32 + k]  (4096 waves x 32)
// [196608..720896)  Epart[b][512]: online-E partials; corr overwrites with final
// [720896..1245184) Ppart[b][512]: plain colsum of P-rows (s < -THR)
// NO memset: k_vu block 0 zeroes the scalar/counter/acc region.

__device__ inline float waveSum(float v){
  #pragma unroll
  for(int off = 32; off > 0; off >>= 1) v += __shfl_down(v, off, 64);
  return v;   // total in lane 0
}
__device__ inline float waveMax(float v){
  #pragma unroll
  for(int off = 32; off > 0; off >>= 1) v = fmaxf(v, __shfl_down(v, off, 64));
  return v;
}
__device__ inline float dot8(float4 x0, float4 x1, float4 v0, float4 v1){
  return x0.x*v0.x + x0.y*v0.y + x0.z*v0.z + x0.w*v0.w
       + x1.x*v1.x + x1.y*v1.y + x1.z*v1.z + x1.w*v1.w;
}
__device__ inline void fma4(float4& acc, float w, float4 x){
  acc.x += w * x.x; acc.y += w * x.y; acc.z += w * x.z; acc.w += w * x.w;
}
__device__ inline void add4(float4& acc, float4 x){
  acc.x += x.x; acc.y += x.y; acc.z += x.z; acc.w += x.w;
}
__device__ inline void scale4(float4& v, float s){
  v.x *= s; v.y *= s; v.z *= s; v.w *= s;
}

// Per-slab partials: vpart[b][j] = sum_{k in slab b} W[k,j] a1[k] (no atomics,
// no zero-init).  Block 0 zeroes the scalar/counter/acc region.
__global__ __launch_bounds__(512) void k_vu(const float* __restrict__ W,
                                            const float* __restrict__ a,
                                            float* __restrict__ vpart,
                                            float* __restrict__ upart,
                                            float* __restrict__ ws){
  int j  = threadIdx.x;
  int b  = blockIdx.x;
  int k0 = b * (MM / NVU);           // 32 rows per slab
  float pv = 0.f, pu = 0.f;
  #pragma unroll 8
  for(int kk = 0; kk < MM / NVU; kk++){
    float w = W[(size_t)(k0 + kk) * MM + j];
    pv += w * a[k0 + kk];
    pu += w * a[MM + k0 + kk];
  }
  vpart[b * MM + j] = pv;
  upart[b * MM + j] = pu;
  if(b == 0){
    if(j < 128) ws[1024 + j] = 0.f;   // sumU, Z, cnt, padding
    ws[1536 + j] = 0.f;               // acc
  }
}

// Pass 1 (online + bucketed, 8-row ILP): prologue reduces vpart/upart into
// LDS; per 8-row group: 16 float4 loads in flight, dual-split accumulators
// (Ea: rows 0-3, Eb: rows 4-7; accU/Ez even/odd) to break serial FMA chains,
// ONE bucket/rescale decision per group.
//   s_i <  -THR : P += x_i (plain colsum), nclip++
//   s_i >= -THR : online E += exp(s_i - m_w) x_i (flash-style running max)
__global__ __launch_bounds__(256) void k_pass1o(const float* __restrict__ x,
                                                const float* __restrict__ vpart,
                                                const float* __restrict__ upart,
                                                float* __restrict__ s,
                                                float* __restrict__ sumU,
                                                float* __restrict__ pmax,
                                                float* __restrict__ Epart,
                                                float* __restrict__ Ppart,
                                                float* __restrict__ zpart,
                                                float* __restrict__ nclipa){
  __shared__ float lsum[4];
  __shared__ float lmax[4];
  __shared__ float ezs[4];
  __shared__ float ncs[4];
  __shared__ float lw[2048];   // 4 waves x 64 lanes x 8 cols
  __shared__ float vul[1024];  // reduced v (0..512) and u (512..1024)
  int tid  = threadIdx.x;
  int lane = tid & 63;
  int wid  = tid >> 6;
  int gw   = blockIdx.x * 4 + wid;

  // ---- prologue: reduce the 16 v/u slabs into LDS ----
  #pragma unroll
  for(int jj = 0; jj < 2; jj++){
    int j = tid + jj * 256;
    float sv = 0.f, su = 0.f;
    #pragma unroll
    for(int bb = 0; bb < NVU; bb++){
      sv += vpart[bb * MM + j];
      su += upart[bb * MM + j];
    }
    vul[j]       = sv;
    vul[512 + j] = su;
  }
  __syncthreads();

  const float4* v4 = (const float4*)vul;
  const float4* u4 = (const float4*)(vul + 512);
  float4 v0 = v4[lane],      v1 = v4[64 + lane];
  float4 u0 = u4[lane],      u1 = u4[64 + lane];
  float accU0 = 0.f, accU1 = 0.f;
  float m_w  = -3.4e38f;
  float Ez0  = 0.f, Ez1 = 0.f;
  float ncl  = 0.f;
  float4 Ea0 = make_float4(0,0,0,0), Ea1 = make_float4(0,0,0,0);
  float4 Eb0 = make_float4(0,0,0,0), Eb1 = make_float4(0,0,0,0);
  float4 P0  = make_float4(0,0,0,0), P1  = make_float4(0,0,0,0);

  int myN = (KK - 1 - gw) / NW + 1;   // rows this wave owns (24 or 25)
  int k = 0;
  for(; k + 8 <= myN; k += 8){
    float4 x0[8], x1[8];
    #pragma unroll
    for(int r = 0; r < 8; r++){
      size_t row = (size_t)gw + (size_t)(k + r) * NW;
      const float4* xr = (const float4*)(x + row * MM);
      x0[r] = xr[lane];
      x1[r] = xr[64 + lane];
    }
    float d[8];
    #pragma unroll
    for(int r = 0; r < 8; r++) d[r] = dot8(x0[r], x1[r], v0, v1);
    #pragma unroll
    for(int r = 0; r < 8; r += 2){
      accU0 += dot8(x0[r],   x1[r],   u0, u1);
      accU1 += dot8(x0[r+1], x1[r+1], u0, u1);
    }
    #pragma unroll
    for(int off = 1; off < 64; off <<= 1){
      #pragma unroll
      for(int r = 0; r < 8; r++) d[r] += __shfl_xor(d[r], off, 64);
    }
    // bucket flags (wave-uniform: d identical in all lanes)
    bool pb[8];
    float e[8];
    #pragma unroll
    for(int r = 0; r < 8; r++){
      pb[r] = d[r] < -THR;
      e[r]  = pb[r] ? -3.4e38f : d[r];
    }
    float g01 = fmaxf(fmaxf(e[0], e[1]), fmaxf(e[2], e[3]));
    float g23 = fmaxf(fmaxf(e[4], e[5]), fmaxf(e[6], e[7]));
    float g   = fmaxf(g01, g23);
    if(g > m_w){
      float sc = __expf(m_w - g);     // exp(-inf)=0 on first E-group
      scale4(Ea0, sc); scale4(Ea1, sc); scale4(Eb0, sc); scale4(Eb1, sc);
      Ez0 *= sc; Ez1 *= sc;
      m_w = g;
    }
    #pragma unroll
    for(int r = 0; r < 4; r++){
      if(pb[r]){ add4(P0, x0[r]); add4(P1, x1[r]); ncl += 1.f; }
      else{
        float w = __expf(d[r] - m_w); Ez0 += w;
        fma4(Ea0, w, x0[r]); fma4(Ea1, w, x1[r]);
      }
    }
    #pragma unroll
    for(int r = 4; r < 8; r++){
      if(pb[r]){ add4(P0, x0[r]); add4(P1, x1[r]); ncl += 1.f; }
      else{
        float w = __expf(d[r] - m_w); Ez1 += w;
        fma4(Eb0, w, x0[r]); fma4(Eb1, w, x1[r]);
      }
    }
    // store s (lanes 0..7, contiguous 32B)
    float s0 = (lane & 1) ? d[1] : d[0];
    float s1 = (lane & 1) ? d[3] : d[2];
    float s2 = (lane & 1) ? d[5] : d[4];
    float s3 = (lane & 1) ? d[7] : d[6];
    float t0 = (lane & 2) ? s1 : s0;
    float t1 = (lane & 2) ? s3 : s2;
    float rr = (lane & 4) ? t1 : t0;
    if(lane < 8) s[gw * SSTR + k + lane] = rr;
  }
  for(; k < myN; k++){
    size_t row = (size_t)gw + (size_t)k * NW;
    const float4* xr = (const float4*)(x + row * MM);
    float4 x0 = xr[lane];
    float4 x1 = xr[64 + lane];
    float d = dot8(x0, x1, v0, v1);
    accU0 += dot8(x0, x1, u0, u1);
    #pragma unroll
    for(int off = 1; off < 64; off <<= 1) d += __shfl_xor(d, off, 64);
    if(d < -THR){
      add4(P0, x0); add4(P1, x1); ncl += 1.f;
    } else {
      if(d > m_w){
        float sc = __expf(m_w - d);
        scale4(Ea0, sc); scale4(Ea1, sc); scale4(Eb0, sc); scale4(Eb1, sc);
        Ez0 *= sc; Ez1 *= sc;
        m_w = d;
      }
      float w = __expf(d - m_w);
      Ez0 += w;
      fma4(Ea0, w, x0); fma4(Ea1, w, x1);
    }
    if(lane == 0) s[gw * SSTR + k] = d;
  }

  // ---- merge split accumulators (same m_w scale) ----
  add4(Ea0, Eb0); add4(Ea1, Eb1);
  float Ez   = Ez0 + Ez1;
  float accU = accU0 + accU1;

  // ---- tail: rescale E to block max, combine E then P, write partials ----
  float us = waveSum(accU);
  if(lane == 0){ lsum[wid] = us; lmax[wid] = m_w; ncs[wid] = ncl; }
  __syncthreads();
  float m_blk = fmaxf(fmaxf(lmax[0], lmax[1]), fmaxf(lmax[2], lmax[3]));
  float sc2 = __expf(m_w - m_blk);    // wave-uniform; 0 if wave had no E-rows
  scale4(Ea0, sc2); scale4(Ea1, sc2);
  if(lane == 0) ezs[wid] = Ez * sc2;
  float4* lw4 = (float4*)lw;
  lw4[wid * 128 + lane * 2]     = Ea0;   // lane l holds cols 4l+q
  lw4[wid * 128 + lane * 2 + 1] = Ea1;   // and cols 256+4l+q
  __syncthreads();
  int l = tid >> 2, q = tid & 3;
  float o0 = lw[0*512 + l*8 + q] + lw[1*512 + l*8 + q]
           + lw[2*512 + l*8 + q] + lw[3*512 + l*8 + q];
  float o1 = lw[0*512 + l*8 + 4 + q] + lw[1*512 + l*8 + 4 + q]
           + lw[2*512 + l*8 + 4 + q] + lw[3*512 + l*8 + 4 + q];
  Epart[(size_t)blockIdx.x * 512 + tid]       = o0;
  Epart[(size_t)blockIdx.x * 512 + 256 + tid] = o1;
  __syncthreads();                    // lw fully read; safe to reuse
  lw4[wid * 128 + lane * 2]     = P0;
  lw4[wid * 128 + lane * 2 + 1] = P1;
  __syncthreads();
  float q0 = lw[0*512 + l*8 + q] + lw[1*512 + l*8 + q]
           + lw[2*512 + l*8 + q] + lw[3*512 + l*8 + q];
  float q1 = lw[0*512 + l*8 + 4 + q] + lw[1*512 + l*8 + 4 + q]
           + lw[2*512 + l*8 + 4 + q] + lw[3*512 + l*8 + 4 + q];
  Ppart[(size_t)blockIdx.x * 512 + tid]       = q0;
  Ppart[(size_t)blockIdx.x * 512 + 256 + tid] = q1;
  if(tid == 0){
    atomicAdd(sumU, lsum[0] + lsum[1] + lsum[2] + lsum[3]);
    pmax[blockIdx.x]   = m_blk;
    zpart[blockIdx.x]  = ezs[0] + ezs[1] + ezs[2] + ezs[3];
    nclipa[blockIdx.x] = ncs[0] + ncs[1] + ncs[2] + ncs[3];
  }
}

// Correction pass: compute c, M; re-read ONLY band rows where the pass1
// bucket disagrees with the true clip test: (s < -THR) XOR (s + c < 0).
// delta weight = +-(e^-M - e^(t-M)).  Fold final combine in place:
// part = Epart*scB + Ppart*e^-M + band;  Z += scB*Ez + e^-M*nclip + bandZ.
__global__ __launch_bounds__(256) void k_corr(const float* __restrict__ x,
                                              const float* __restrict__ s,
                                              const float* __restrict__ b,
                                              const float* __restrict__ a,
                                              const float* __restrict__ sumU,
                                              const float* __restrict__ pmax,
                                              float* __restrict__ Epart,
                                              const float* __restrict__ Ppart,
                                              const float* __restrict__ zpart,
                                              const float* __restrict__ nclipa,
                                              float* __restrict__ Z){
  __shared__ float red[8];
  __shared__ float czs[4];
  __shared__ float lw[2048];
  int tid  = threadIdx.x;
  int lane = tid & 63;
  int wid  = tid >> 6;
  int gw   = blockIdx.x * 4 + wid;

  // ---- prologue: c = b.(a1+a2) + sumU/K ; M = max(0, max_i s_i + c) ----
  float tp = b[tid]       * (a[tid]       + a[MM + tid])
           + b[tid + 256] * (a[tid + 256] + a[MM + tid + 256]);
  float mx = fmaxf(fmaxf(pmax[tid], pmax[tid + 256]),
                   fmaxf(pmax[tid + 512], pmax[tid + 768]));
  float wsum = waveSum(tp);
  mx = waveMax(mx);
  if(lane == 0){ red[wid] = wsum; red[4 + wid] = mx; }
  __syncthreads();
  float c  = sumU[0] * (1.0f / (float)KK) + red[0] + red[1] + red[2] + red[3];
  float mg = fmaxf(fmaxf(red[4], red[5]), fmaxf(red[6], red[7]));
  // mg is max over E-rows only; P-rows have s < -THR < mg in practice, and
  // even degenerate cases keep M >= 0 >= t for clipped rows (relu floor).
  float M  = fmaxf(0.f, mg + c);
  float eM = __expf(-M);

  // ---- band loop: rows where (s < -THR) XOR (t < 0); typically ~6-10% ----
  float4 C0 = make_float4(0,0,0,0), C1 = make_float4(0,0,0,0);
  float Cz = 0.f;
  int myN = (KK - 1 - gw) / NW + 1;
  const float4* s4 = (const float4*)(s + gw * SSTR);
  #pragma unroll
  for(int g2 = 0; g2 < 7; g2++){
    int kb = g2 * 4;
    if(kb >= myN) break;
    float4 sv = s4[g2];
    float svv[4] = {sv.x, sv.y, sv.z, sv.w};
    #pragma unroll
    for(int r = 0; r < 4; r++){
      int k = kb + r;
      float si = svv[r];
      float t  = si + c;
      bool pb  = si < -THR;     // pass1 bucket: plain-sum
      bool cl  = t  < 0.f;      // true clip
      if(k < myN && (pb != cl)){
        // pass1-assigned weight: pb ? e^-M : e^(t-M); true: cl ? e^-M : e^(t-M)
        float d  = eM - __expf(t - M);
        float kap = cl ? d : -d;
        size_t row = (size_t)gw + (size_t)k * NW;
        const float4* xr = (const float4*)(x + row * MM);
        float4 x0 = xr[lane], x1 = xr[64 + lane];
        fma4(C0, kap, x0); fma4(C1, kap, x1); Cz += kap;
      }
    }
  }

  // ---- combine band C across waves; fold final partial in place; Z ----
  __syncthreads();                 // red fully consumed above
  float4* lw4 = (float4*)lw;
  lw4[wid * 128 + lane * 2]     = C0;
  lw4[wid * 128 + lane * 2 + 1] = C1;
  if(lane == 0) czs[wid] = Cz;     // Cz identical across lanes (uniform kap)
  __syncthreads();
  int l = tid >> 2, q = tid & 3;
  float o0 = lw[0*512 + l*8 + q] + lw[1*512 + l*8 + q]
           + lw[2*512 + l*8 + q] + lw[3*512 + l*8 + q];
  float o1 = lw[0*512 + l*8 + 4 + q] + lw[1*512 + l*8 + 4 + q]
           + lw[2*512 + l*8 + 4 + q] + lw[3*512 + l*8 + 4 + q];
  float scB = __expf(c - M + pmax[blockIdx.x]);   // <= 1 by construction
  size_t base = (size_t)blockIdx.x * 512;
  Epart[base + tid]       = Epart[base + tid]       * scB
                          + Ppart[base + tid]       * eM + o0;
  Epart[base + 256 + tid] = Epart[base + 256 + tid] * scB
                          + Ppart[base + 256 + tid] * eM + o1;
  if(tid == 0)
    atomicAdd(Z, czs[0] + czs[1] + czs[2] + czs[3]
                 + scB * zpart[blockIdx.x] + eM * nclipa[blockIdx.x]);
}

// Reduce part[1024][512] -> acc, last block divides by Z and writes out.
__global__ __launch_bounds__(256) void k_out(const float* __restrict__ part,
                                             float* __restrict__ acc,
                                             const float* __restrict__ Z,
                                             int* __restrict__ cnt,
                                             float* __restrict__ out){
  __shared__ int lastf;
  int tid = threadIdx.x;
  const float* p = part + (size_t)blockIdx.x * (NB1 / NOUT) * 512;
  float s0 = 0.f, s1 = 0.f;
  #pragma unroll 8
  for(int bb = 0; bb < NB1 / NOUT; bb++){
    s0 += p[bb * 512 + tid];
    s1 += p[bb * 512 + 256 + tid];
  }
  atomicAdd(&acc[tid],       s0);
  atomicAdd(&acc[tid + 256], s1);
  __threadfence();
  if(tid == 0) lastf = (atomicAdd(cnt, 1) == NOUT - 1) ? 1 : 0;
  __syncthreads();
  if(lastf){
    float z = Z[0];   // written by previous dispatch — safe plain read
    float v0 = atomicAdd(&acc[tid],       0.0f);  // coherent read of atomics
    float v1 = atomicAdd(&acc[tid + 256], 0.0f);
    out[tid]       = v0 / z;
    out[tid + 256] = v1 / z;
  }
}

extern "C" void kernel_launch(void* const* d_in, const int* in_sizes, int n_in,
                              void* d_out, int out_size, void* d_ws, size_t ws_size,
                              hipStream_t stream) {
  const float* x = (const float*)d_in[0];
  const float* W = (const float*)d_in[1];
  const float* b = (const float*)d_in[2];
  const float* a = (const float*)d_in[3];
  float* ws  = (float*)d_ws;
  float* out = (float*)d_out;

  float* sumU   = ws + 1024;
  float* Z      = ws + 1025;
  int*   cnt    = (int*)(ws + 1026);
  float* acc    = ws + 1536;
  float* pmax   = ws + 2048;
  float* zpart  = ws + 3072;
  float* vpart  = ws + 4096;
  float* upart  = ws + 12288;
  float* nclipa = ws + 20480;
  float* s      = ws + 32768;
  float* Epart  = ws + 196608;
  float* Ppart  = ws + 720896;

  k_vu    <<<NVU,  512, 0, stream>>>(W, a, vpart, upart, ws);
  k_pass1o<<<NB1,  256, 0, stream>>>(x, vpart, upart, s, sumU, pmax,
                                     Epart, Ppart, zpart, nclipa);
  k_corr  <<<NB1,  256, 0, stream>>>(x, s, b, a, sumU, pmax,
                                     Epart, Ppart, zpart, nclipa, Z);
  k_out   <<<NOUT, 256, 0, stream>>>(Epart, acc, Z, cnt, out);
}